// Round 1
// baseline (200.108 us; speedup 1.0000x reference)
//
#include <hip/hip_runtime.h>

// EGNN: B=64, N=128, coors/vel dim 2, feature D=3 (t broadcast), M=16, L=2.
// Layer l: per edge (i,j): e1 = silu(W1^T [t_i,t_i,t_i,t_j,t_j,t_j,dist,1] + b1)
//          m = silu(W2^T e1 + b2); sm = silu(m); h = silu(Wc1^T sm + bc1)
//          w_ij = Wc2^T h + bc2;  agg_i = sum_j w_ij * (c_i - c_j)
//          vel = (t_i*sum(Wv)+bv)*vel + agg; coors += vel; selu both.
// Head (per node): x = selu([c,v]); x32 = selu(Wconv1 x + b); y = Wconv2 x32 + b.

#define NB 64
#define NN 128

__device__ __forceinline__ float silu_f(float x) {
    float e = __expf(-x);
    return x * __builtin_amdgcn_rcpf(1.0f + e);
}

__device__ __forceinline__ float selu_f(float x) {
    const float alpha = 1.6732632423543772f;
    const float scale = 1.0507009873554805f;
    float neg = alpha * (__expf(x) - 1.0f);
    return scale * (x > 0.0f ? x : neg);
}

template <bool DO_HEAD>
__global__ __launch_bounds__(256) void egnn_layer(
    const float* __restrict__ t,
    const float* __restrict__ coors_in,
    const float* __restrict__ vel_in,
    const float* __restrict__ We1, const float* __restrict__ be1,
    const float* __restrict__ We2, const float* __restrict__ be2,
    const float* __restrict__ Wc1, const float* __restrict__ bc1,
    const float* __restrict__ Wc2, const float* __restrict__ bc2,
    const float* __restrict__ Wv,  const float* __restrict__ bv,
    const float* __restrict__ Wconv1, const float* __restrict__ bconv1,
    const float* __restrict__ Wconv2, const float* __restrict__ bconv2,
    int layer,
    float* __restrict__ coors_out, float* __restrict__ vel_out,
    float* __restrict__ out)
{
    const int lane = threadIdx.x & 63;
    const int wave = threadIdx.x >> 6;
    const int row  = blockIdx.x * 4 + wave;   // 0..8191 = b*128+i
    const int b    = row >> 7;
    const int i    = row & 127;

    // per-layer weight bases (wave-uniform -> scalar loads)
    const float* We1l = We1 + layer * 8 * 16;
    const float* be1l = be1 + layer * 16;
    const float* We2l = We2 + layer * 16 * 16;
    const float* be2l = be2 + layer * 16;
    const float* Wc1l = Wc1 + layer * 16 * 64;
    const float* bc1l = bc1 + layer * 64;
    const float* Wc2l = Wc2 + layer * 64;
    const float  bc2l = bc2[layer];
    const float  wv_s = Wv[layer * 3 + 0] + Wv[layer * 3 + 1] + Wv[layer * 3 + 2];
    const float  bvl  = bv[layer];

    const float ti = t[b * NN + i];
    const float2* cin = (const float2*)coors_in + b * NN;
    const float2 ci = cin[i];

    // two edges per lane: j0 = lane, j1 = lane + 64
    const int j0 = lane, j1 = lane + 64;
    const float2 cj0 = cin[j0];
    const float2 cj1 = cin[j1];
    const float tj0 = t[b * NN + j0];
    const float tj1 = t[b * NN + j1];
    const float rx0 = ci.x - cj0.x, ry0 = ci.y - cj0.y;
    const float rx1 = ci.x - cj1.x, ry1 = ci.y - cj1.y;
    const float d0 = rx0 * rx0 + ry0 * ry0;
    const float d1 = rx1 * rx1 + ry1 * ry1;

    float sm0[16], sm1[16];
    {
        float e10[16], e11[16];
#pragma unroll
        for (int o = 0; o < 16; ++o) {
            // collapse hi(3)/hj(3)/dist/edge rows of We1 (uniform scalar math)
            float a  = We1l[0 * 16 + o] + We1l[1 * 16 + o] + We1l[2 * 16 + o];
            float bb = We1l[3 * 16 + o] + We1l[4 * 16 + o] + We1l[5 * 16 + o];
            float c  = We1l[6 * 16 + o];
            float dd = We1l[7 * 16 + o] + be1l[o];
            float base = ti * a + dd;
            e10[o] = silu_f(base + tj0 * bb + d0 * c);
            e11[o] = silu_f(base + tj1 * bb + d1 * c);
        }
#pragma unroll 4
        for (int o = 0; o < 16; ++o) {
            float s0 = be2l[o], s1 = s0;
#pragma unroll
            for (int k = 0; k < 16; ++k) {
                float w = We2l[k * 16 + o];
                s0 += e10[k] * w;
                s1 += e11[k] * w;
            }
            sm0[o] = silu_f(silu_f(s0));
            sm1[o] = silu_f(silu_f(s1));
        }
    }

    float w0 = bc2l, w1 = bc2l;
#pragma unroll 4
    for (int k = 0; k < 64; ++k) {
        float s0 = bc1l[k], s1 = s0;
#pragma unroll
        for (int q = 0; q < 16; ++q) {
            float w = Wc1l[q * 64 + k];
            s0 += sm0[q] * w;
            s1 += sm1[q] * w;
        }
        float wk = Wc2l[k];
        w0 += silu_f(s0) * wk;
        w1 += silu_f(s1) * wk;
    }

    // agg over this lane's two edges, then wave butterfly reduce
    float ax = w0 * rx0 + w1 * rx1;
    float ay = w0 * ry0 + w1 * ry1;
#pragma unroll
    for (int m = 32; m >= 1; m >>= 1) {
        ax += __shfl_xor(ax, m, 64);
        ay += __shfl_xor(ay, m, 64);
    }

    if (lane == 0) {
        const float2* vin = (const float2*)vel_in + b * NN;
        const float2 vi = vin[i];
        const float phi = ti * wv_s + bvl;
        float vx = phi * vi.x + ax;
        float vy = phi * vi.y + ay;
        float cx = ci.x + vx;
        float cy = ci.y + vy;
        cx = selu_f(cx); cy = selu_f(cy);
        vx = selu_f(vx); vy = selu_f(vy);
        if (!DO_HEAD) {
            float2* cout = (float2*)coors_out + b * NN;
            float2* vout = (float2*)vel_out + b * NN;
            cout[i] = make_float2(cx, cy);
            vout[i] = make_float2(vx, vy);
        } else {
            const float x0 = selu_f(cx), x1 = selu_f(cy);
            const float x2 = selu_f(vx), x3 = selu_f(vy);
            float y[4];
#pragma unroll
            for (int o = 0; o < 4; ++o) y[o] = bconv2[o];
#pragma unroll 8
            for (int c = 0; c < 32; ++c) {
                float xc = selu_f(bconv1[c] + x0 * Wconv1[c * 4 + 0]
                                            + x1 * Wconv1[c * 4 + 1]
                                            + x2 * Wconv1[c * 4 + 2]
                                            + x3 * Wconv1[c * 4 + 3]);
#pragma unroll
                for (int o = 0; o < 4; ++o) y[o] += xc * Wconv2[o * 32 + c];
            }
            const int idx = (b * NN + i) * 2;
            out[idx]     = y[0];
            out[idx + 1] = y[1];
            out[NB * NN * 2 + idx]     = y[2];
            out[NB * NN * 2 + idx + 1] = y[3];
        }
    }
}

extern "C" void kernel_launch(void* const* d_in, const int* in_sizes, int n_in,
                              void* d_out, int out_size, void* d_ws, size_t ws_size,
                              hipStream_t stream) {
    const float* t      = (const float*)d_in[0];
    const float* coors  = (const float*)d_in[1];
    const float* vel    = (const float*)d_in[2];
    const float* We1    = (const float*)d_in[3];
    const float* be1    = (const float*)d_in[4];
    const float* We2    = (const float*)d_in[5];
    const float* be2    = (const float*)d_in[6];
    const float* Wc1    = (const float*)d_in[7];
    const float* bc1    = (const float*)d_in[8];
    const float* Wc2    = (const float*)d_in[9];
    const float* bc2    = (const float*)d_in[10];
    const float* Wv     = (const float*)d_in[11];
    const float* bv     = (const float*)d_in[12];
    const float* Wconv1 = (const float*)d_in[13];
    const float* bconv1 = (const float*)d_in[14];
    const float* Wconv2 = (const float*)d_in[15];
    const float* bconv2 = (const float*)d_in[16];
    float* out = (float*)d_out;

    float* ws     = (float*)d_ws;
    float* coors1 = ws;                 // B*N*2 floats
    float* vel1   = ws + NB * NN * 2;   // B*N*2 floats

    const dim3 grid(2048), block(256);  // 8192 rows, 1 wave per row

    egnn_layer<false><<<grid, block, 0, stream>>>(
        t, coors, vel, We1, be1, We2, be2, Wc1, bc1, Wc2, bc2, Wv, bv,
        Wconv1, bconv1, Wconv2, bconv2, 0, coors1, vel1, nullptr);

    egnn_layer<true><<<grid, block, 0, stream>>>(
        t, coors1, vel1, We1, be1, We2, be2, Wc1, bc1, Wc2, bc2, Wv, bv,
        Wconv1, bconv1, Wconv2, bconv2, 1, nullptr, nullptr, out);
}

// Round 2
// 177.497 us; speedup vs baseline: 1.1274x; 1.1274x over previous
//
#include <hip/hip_runtime.h>

// EGNN via MFMA: B=64, N=128, M=16, L=2. Per wave: one (b,i) row, 8 tiles of
// 16 edges. Weights = A operand (wave-uniform), activations = B operand.
// K=32 slots: real K<=16 duplicated against [W_hi; W_lo] bf16 splits -> ~16-bit
// effective weight precision at zero extra MFMA cost.

#define NB 64
#define NN 128

typedef __attribute__((ext_vector_type(8))) short short8;
typedef __attribute__((ext_vector_type(4))) float floatx4;

__device__ __forceinline__ unsigned short f2bf(float x) {
    unsigned u = __float_as_uint(x);
    return (unsigned short)((u + 0x7FFFu + ((u >> 16) & 1u)) >> 16);
}
__device__ __forceinline__ float bf2f(unsigned short b) {
    return __uint_as_float(((unsigned)b) << 16);
}
__device__ __forceinline__ unsigned pack2(float x, float y) {
    return (unsigned)f2bf(x) | ((unsigned)f2bf(y) << 16);
}
__device__ __forceinline__ float silu_f(float x) {
    float e = __expf(-x);
    return x * __builtin_amdgcn_rcpf(1.0f + e);
}
__device__ __forceinline__ float selu_f(float x) {
    const float alpha = 1.6732632423543772f;
    const float scale = 1.0507009873554805f;
    float neg = alpha * (__expf(x) - 1.0f);
    return scale * (x > 0.0f ? x : neg);
}

template <bool DO_HEAD>
__global__ __launch_bounds__(256) void egnn_layer(
    const float* __restrict__ t,
    const float* __restrict__ coors_in,
    const float* __restrict__ vel_in,
    const float* __restrict__ We1, const float* __restrict__ be1,
    const float* __restrict__ We2, const float* __restrict__ be2,
    const float* __restrict__ Wc1, const float* __restrict__ bc1,
    const float* __restrict__ Wc2, const float* __restrict__ bc2,
    const float* __restrict__ Wv,  const float* __restrict__ bv,
    const float* __restrict__ Wconv1, const float* __restrict__ bconv1,
    const float* __restrict__ Wconv2, const float* __restrict__ bconv2,
    int layer,
    float* __restrict__ coors_out, float* __restrict__ vel_out,
    float* __restrict__ out)
{
    const int l   = threadIdx.x & 63;
    const int wv  = threadIdx.x >> 6;
    const int row = blockIdx.x * 4 + wv;      // b*128 + i
    const int b   = row >> 7;
    const int i   = row & 127;
    const int q   = l >> 4;                   // quad 0..3
    const int em  = l & 15;                   // edge-in-tile / weight row

    const float* We1l = We1 + layer * 8 * 16;
    const float* be1l = be1 + layer * 16;
    const float* We2l = We2 + layer * 16 * 16;
    const float* be2l = be2 + layer * 16;
    const float* Wc1l = Wc1 + layer * 16 * 64;
    const float* bc1l = bc1 + layer * 64;
    const float* Wc2l = Wc2 + layer * 64;
    const float  wv_s = Wv[layer * 3 + 0] + Wv[layer * 3 + 1] + Wv[layer * 3 + 2];
    const float  bvl  = bv[layer];

    // ---- prologue: wave-uniform weight fragments ----
    // Stage A: collapsed We1. inputs [ti_h,ti_l,tj_h,tj_l,d_h,d_l,0,0] x2 quads
    float Aw = We1l[0 * 16 + em] + We1l[1 * 16 + em] + We1l[2 * 16 + em];
    float Bw = We1l[3 * 16 + em] + We1l[4 * 16 + em] + We1l[5 * 16 + em];
    float Cw = We1l[6 * 16 + em];
    unsigned short Ah = f2bf(Aw), Al = f2bf(Aw - bf2f(Ah));
    unsigned short Bh = f2bf(Bw), Bl = f2bf(Bw - bf2f(Bh));
    unsigned short Ch = f2bf(Cw), Cl = f2bf(Cw - bf2f(Ch));
    short8 wA;
    {
        short h0 = (q == 0) ? (short)Ah : ((q == 1) ? (short)Al : (short)0);
        short h1 = (q == 0) ? (short)Bh : ((q == 1) ? (short)Bl : (short)0);
        short h2 = (q == 0) ? (short)Ch : ((q == 1) ? (short)Cl : (short)0);
        wA[0] = h0; wA[1] = h0; wA[2] = h1; wA[3] = h1;
        wA[4] = h2; wA[5] = h2; wA[6] = 0;  wA[7] = 0;
    }
    floatx4 biasA;
#pragma unroll
    for (int r = 0; r < 4; ++r)
        biasA[r] = We1l[7 * 16 + 4 * q + r] + be1l[4 * q + r];   // edge feature == 1

    // Stage B: We2 (16x16), A[m][k] = k<16 ? hi(We2[k][m]) : lo(We2[k-16][m])
    short8 wB;
#pragma unroll
    for (int j = 0; j < 8; ++j) {
        int k = q * 8 + j;
        float w = We2l[(k & 15) * 16 + em];
        unsigned short hv = f2bf(w);
        unsigned short lv = f2bf(w - bf2f(hv));
        wB[j] = (k < 16) ? (short)hv : (short)lv;
    }
    floatx4 biasB;
#pragma unroll
    for (int r = 0; r < 4; ++r) biasB[r] = be2l[4 * q + r];

    // Stage C: Wc1 (16 -> 64), 4 fragments of 16 out-channels
    short8 wC[4];
    floatx4 biasC[4];
    float wc2v[16];
#pragma unroll
    for (int f = 0; f < 4; ++f) {
#pragma unroll
        for (int j = 0; j < 8; ++j) {
            int k = q * 8 + j;
            float w = Wc1l[(k & 15) * 64 + 16 * f + em];
            unsigned short hv = f2bf(w);
            unsigned short lv = f2bf(w - bf2f(hv));
            wC[f][j] = (k < 16) ? (short)hv : (short)lv;
        }
#pragma unroll
        for (int r = 0; r < 4; ++r) {
            biasC[f][r]    = bc1l[16 * f + 4 * q + r];
            wc2v[f * 4 + r] = Wc2l[16 * f + 4 * q + r];
        }
    }
    const float bc2q = (q == 0) ? bc2[layer] : 0.0f;

    // ---- row data ----
    const float ti = t[b * NN + i];
    unsigned short tih = f2bf(ti), til = f2bf(ti - bf2f(tih));
    const float2* cin = (const float2*)coors_in + b * NN;
    const float2 ci = cin[i];

    // shuffle sources for C-layout -> B-operand transform
    const int sA = em + ((q & 1) << 5);
    const int sB = sA + 16;

    float ax = 0.0f, ay = 0.0f;

#pragma unroll 2
    for (int tt = 0; tt < 8; ++tt) {
        const int j = tt * 16 + em;
        const float tj = t[b * NN + j];
        const float2 cj = cin[j];
        const float rx = ci.x - cj.x, ry = ci.y - cj.y;
        const float dist = rx * rx + ry * ry;
        unsigned short tjh = f2bf(tj),   tjl = f2bf(tj - bf2f(tjh));
        unsigned short dh  = f2bf(dist), dl  = f2bf(dist - bf2f(dh));

        short8 bA;
        const bool act = (q < 2);
        bA[0] = act ? (short)tih : (short)0;
        bA[1] = act ? (short)til : (short)0;
        bA[2] = act ? (short)tjh : (short)0;
        bA[3] = act ? (short)tjl : (short)0;
        bA[4] = act ? (short)dh  : (short)0;
        bA[5] = act ? (short)dl  : (short)0;
        bA[6] = 0; bA[7] = 0;

        // Stage A: e1 = silu(W1 . x + b1)
        floatx4 accA = __builtin_amdgcn_mfma_f32_16x16x32_bf16(wA, bA, biasA, 0, 0, 0);
        unsigned P0 = pack2(silu_f(accA[0]), silu_f(accA[1]));
        unsigned P1 = pack2(silu_f(accA[2]), silu_f(accA[3]));
        uint4 tb;
        tb.x = (unsigned)__shfl((int)P0, sA, 64);
        tb.y = (unsigned)__shfl((int)P1, sA, 64);
        tb.z = (unsigned)__shfl((int)P0, sB, 64);
        tb.w = (unsigned)__shfl((int)P1, sB, 64);
        short8 bB = __builtin_bit_cast(short8, tb);

        // Stage B: m = silu(W2 . e1 + b2); sm = silu(m)
        floatx4 accB = __builtin_amdgcn_mfma_f32_16x16x32_bf16(wB, bB, biasB, 0, 0, 0);
        unsigned Q0 = pack2(silu_f(silu_f(accB[0])), silu_f(silu_f(accB[1])));
        unsigned Q1 = pack2(silu_f(silu_f(accB[2])), silu_f(silu_f(accB[3])));
        uint4 tc;
        tc.x = (unsigned)__shfl((int)Q0, sA, 64);
        tc.y = (unsigned)__shfl((int)Q1, sA, 64);
        tc.z = (unsigned)__shfl((int)Q0, sB, 64);
        tc.w = (unsigned)__shfl((int)Q1, sB, 64);
        short8 bC = __builtin_bit_cast(short8, tc);

        // Stage C: h = silu(Wc1 . sm + bc1), 64 channels in 4 fragments
        floatx4 h0 = __builtin_amdgcn_mfma_f32_16x16x32_bf16(wC[0], bC, biasC[0], 0, 0, 0);
        floatx4 h1 = __builtin_amdgcn_mfma_f32_16x16x32_bf16(wC[1], bC, biasC[1], 0, 0, 0);
        floatx4 h2 = __builtin_amdgcn_mfma_f32_16x16x32_bf16(wC[2], bC, biasC[2], 0, 0, 0);
        floatx4 h3 = __builtin_amdgcn_mfma_f32_16x16x32_bf16(wC[3], bC, biasC[3], 0, 0, 0);

        // Stage D: per-lane partial of w_ij = bc2 + h . Wc2 (16 of 64 channels)
        float wp = bc2q;
#pragma unroll
        for (int r = 0; r < 4; ++r) wp += silu_f(h0[r]) * wc2v[0 + r];
#pragma unroll
        for (int r = 0; r < 4; ++r) wp += silu_f(h1[r]) * wc2v[4 + r];
#pragma unroll
        for (int r = 0; r < 4; ++r) wp += silu_f(h2[r]) * wc2v[8 + r];
#pragma unroll
        for (int r = 0; r < 4; ++r) wp += silu_f(h3[r]) * wc2v[12 + r];

        ax += wp * rx;
        ay += wp * ry;
    }

    // reduce agg over all 64 lanes (quads hold channel-partials, em holds edges)
#pragma unroll
    for (int m = 32; m >= 1; m >>= 1) {
        ax += __shfl_xor(ax, m, 64);
        ay += __shfl_xor(ay, m, 64);
    }

    if (l == 0) {
        const float2* vin = (const float2*)vel_in + b * NN;
        const float2 vi = vin[i];
        const float phi = ti * wv_s + bvl;
        float vx = phi * vi.x + ax;
        float vy = phi * vi.y + ay;
        float cx = ci.x + vx;
        float cy = ci.y + vy;
        cx = selu_f(cx); cy = selu_f(cy);
        vx = selu_f(vx); vy = selu_f(vy);
        if (!DO_HEAD) {
            float2* cout = (float2*)coors_out + b * NN;
            float2* vout = (float2*)vel_out + b * NN;
            cout[i] = make_float2(cx, cy);
            vout[i] = make_float2(vx, vy);
        } else {
            const float x0 = selu_f(cx), x1 = selu_f(cy);
            const float x2 = selu_f(vx), x3 = selu_f(vy);
            float y[4];
#pragma unroll
            for (int o = 0; o < 4; ++o) y[o] = bconv2[o];
#pragma unroll 8
            for (int c = 0; c < 32; ++c) {
                float xc = selu_f(bconv1[c] + x0 * Wconv1[c * 4 + 0]
                                            + x1 * Wconv1[c * 4 + 1]
                                            + x2 * Wconv1[c * 4 + 2]
                                            + x3 * Wconv1[c * 4 + 3]);
#pragma unroll
                for (int o = 0; o < 4; ++o) y[o] += xc * Wconv2[o * 32 + c];
            }
            const int idx = (b * NN + i) * 2;
            out[idx]     = y[0];
            out[idx + 1] = y[1];
            out[NB * NN * 2 + idx]     = y[2];
            out[NB * NN * 2 + idx + 1] = y[3];
        }
    }
}

extern "C" void kernel_launch(void* const* d_in, const int* in_sizes, int n_in,
                              void* d_out, int out_size, void* d_ws, size_t ws_size,
                              hipStream_t stream) {
    const float* t      = (const float*)d_in[0];
    const float* coors  = (const float*)d_in[1];
    const float* vel    = (const float*)d_in[2];
    const float* We1    = (const float*)d_in[3];
    const float* be1    = (const float*)d_in[4];
    const float* We2    = (const float*)d_in[5];
    const float* be2    = (const float*)d_in[6];
    const float* Wc1    = (const float*)d_in[7];
    const float* bc1    = (const float*)d_in[8];
    const float* Wc2    = (const float*)d_in[9];
    const float* bc2    = (const float*)d_in[10];
    const float* Wv     = (const float*)d_in[11];
    const float* bv     = (const float*)d_in[12];
    const float* Wconv1 = (const float*)d_in[13];
    const float* bconv1 = (const float*)d_in[14];
    const float* Wconv2 = (const float*)d_in[15];
    const float* bconv2 = (const float*)d_in[16];
    float* out = (float*)d_out;

    float* ws     = (float*)d_ws;
    float* coors1 = ws;                 // B*N*2 floats
    float* vel1   = ws + NB * NN * 2;   // B*N*2 floats

    const dim3 grid(2048), block(256);  // 8192 rows, 1 wave per row

    egnn_layer<false><<<grid, block, 0, stream>>>(
        t, coors, vel, We1, be1, We2, be2, Wc1, bc1, Wc2, bc2, Wv, bv,
        Wconv1, bconv1, Wconv2, bconv2, 0, coors1, vel1, nullptr);

    egnn_layer<true><<<grid, block, 0, stream>>>(
        t, coors1, vel1, We1, be1, We2, be2, Wc1, bc1, Wc2, bc2, Wv, bv,
        Wconv1, bconv1, Wconv2, bconv2, 1, nullptr, nullptr, out);
}

// Round 3
// 152.835 us; speedup vs baseline: 1.3093x; 1.1614x over previous
//
#include <hip/hip_runtime.h>

// EGNN, MFMA core + lean VALU. B=64, N=128, M=16, L=2.
// Per wave: one (b,i) row, 8 tiles of 16 edges j.
//  Stage A (8->16, collapsed to 3 scalars ti/tj/dist): fp32 VALU, C-layout.
//  Stage B (16->16) & C (16->64): mfma_f32_16x16x32_bf16, weights=A operand
//  with [hi;lo] bf16 split in the K=32 slots (~16-bit weight precision).
//  Stage D (64->1): per-lane fp32 dot + wave butterfly reduce.
// Weight fragments precomputed once into d_ws by egnn_prep (1 block).

#define NB 64
#define NN 128

typedef __attribute__((ext_vector_type(8))) short short8;
typedef __attribute__((ext_vector_type(4))) float floatx4;

__device__ __forceinline__ unsigned short f2bf(float x) {
    unsigned u = __float_as_uint(x);
    return (unsigned short)((u + 0x7FFFu + ((u >> 16) & 1u)) >> 16);
}
__device__ __forceinline__ float bf2f(unsigned short b) {
    return __uint_as_float(((unsigned)b) << 16);
}
// pack two f32 -> bf16x2 (round-half-up): 2 adds + 1 v_perm
__device__ __forceinline__ unsigned packbf(float x, float y) {
    unsigned xb = __float_as_uint(x) + 0x8000u;
    unsigned yb = __float_as_uint(y) + 0x8000u;
    return __builtin_amdgcn_perm(yb, xb, 0x07060302u);
}
__device__ __forceinline__ float silu_f(float x) {
    float e = __expf(-x);
    return x * __builtin_amdgcn_rcpf(1.0f + e);
}
__device__ __forceinline__ float selu_f(float x) {
    const float alpha = 1.6732632423543772f;
    const float scale = 1.0507009873554805f;
    float neg = alpha * (__expf(x) - 1.0f);
    return scale * (x > 0.0f ? x : neg);
}

// ---- prep: build collapsed We1 coeffs + bf16 hi/lo weight fragments ----
// ws float layout per layer (stride 2048 floats):
//   [0,16)A [16,32)B [32,48)C [48,64)D(+be1)  [64,320) wB frags  [320,1344) wC frags
__global__ __launch_bounds__(128) void egnn_prep(
    const float* __restrict__ We1, const float* __restrict__ be1,
    const float* __restrict__ We2, const float* __restrict__ Wc1,
    float* __restrict__ prep)
{
    const int layer = threadIdx.x >> 6;
    const int l = threadIdx.x & 63;
    const int q = l >> 4, em = l & 15;
    const float* We1l = We1 + layer * 128;
    const float* be1l = be1 + layer * 16;
    const float* We2l = We2 + layer * 256;
    const float* Wc1l = Wc1 + layer * 1024;
    float* P = prep + layer * 2048;

    if (l < 16) {
        P[l]      = We1l[l] + We1l[16 + l] + We1l[32 + l];
        P[16 + l] = We1l[48 + l] + We1l[64 + l] + We1l[80 + l];
        P[32 + l] = We1l[96 + l];
        P[48 + l] = We1l[112 + l] + be1l[l];
    }
    // wB: A[m=em][k=q*8+j], k<16 -> hi(We2[k][m]), else lo(We2[k-16][m])
    {
        unsigned wb[4];
#pragma unroll
        for (int d = 0; d < 4; ++d) {
            unsigned short sv[2];
#pragma unroll
            for (int e = 0; e < 2; ++e) {
                int k = q * 8 + 2 * d + e;
                float w = We2l[(k & 15) * 16 + em];
                unsigned short hv = f2bf(w);
                unsigned short lv = f2bf(w - bf2f(hv));
                sv[e] = (k < 16) ? hv : lv;
            }
            wb[d] = (unsigned)sv[0] | ((unsigned)sv[1] << 16);
        }
        *(uint4*)((unsigned*)(P + 64) + l * 4) = make_uint4(wb[0], wb[1], wb[2], wb[3]);
    }
    // wC: 4 fragments of 16 out-channels each
#pragma unroll
    for (int f = 0; f < 4; ++f) {
        unsigned wc[4];
#pragma unroll
        for (int d = 0; d < 4; ++d) {
            unsigned short sv[2];
#pragma unroll
            for (int e = 0; e < 2; ++e) {
                int k = q * 8 + 2 * d + e;
                float w = Wc1l[(k & 15) * 64 + 16 * f + em];
                unsigned short hv = f2bf(w);
                unsigned short lv = f2bf(w - bf2f(hv));
                sv[e] = (k < 16) ? hv : lv;
            }
            wc[d] = (unsigned)sv[0] | ((unsigned)sv[1] << 16);
        }
        *(uint4*)((unsigned*)(P + 320) + l * 16 + f * 4) = make_uint4(wc[0], wc[1], wc[2], wc[3]);
    }
}

template <bool DO_HEAD>
__global__ __launch_bounds__(256) void egnn_layer(
    const float* __restrict__ t,
    const float* __restrict__ coors_in,
    const float* __restrict__ vel_in,
    const float* __restrict__ prep,
    const float* __restrict__ be2,
    const float* __restrict__ bc1,
    const float* __restrict__ Wc2, const float* __restrict__ bc2,
    const float* __restrict__ Wv,  const float* __restrict__ bv,
    const float* __restrict__ Wconv1, const float* __restrict__ bconv1,
    const float* __restrict__ Wconv2, const float* __restrict__ bconv2,
    int layer,
    float* __restrict__ coors_out, float* __restrict__ vel_out,
    float* __restrict__ out)
{
    const int l   = threadIdx.x & 63;
    const int wvi = threadIdx.x >> 6;
    const int row = blockIdx.x * 4 + wvi;     // b*128 + i
    const int b   = row >> 7;
    const int i   = row & 127;
    const int q   = l >> 4;                   // quad 0..3
    const int em  = l & 15;                   // edge-in-tile / out-row group

    const float* P    = prep + layer * 2048;
    const float* be2l = be2 + layer * 16;
    const float* bc1l = bc1 + layer * 64;
    const float* Wc2l = Wc2 + layer * 64;
    const float  wv_s = Wv[layer * 3 + 0] + Wv[layer * 3 + 1] + Wv[layer * 3 + 2];
    const float  bvl  = bv[layer];

    // prologue: per-lane fragment loads (all from L1/L2-hot prep + params)
    const float4 a4 = *(const float4*)(P + 0  + q * 4);
    const float4 b4 = *(const float4*)(P + 16 + q * 4);
    const float4 c4 = *(const float4*)(P + 32 + q * 4);
    const float4 d4 = *(const float4*)(P + 48 + q * 4);
    const short8 wB = __builtin_bit_cast(short8, *(const uint4*)((const unsigned*)(P + 64) + l * 4));
    short8 wC[4];
#pragma unroll
    for (int f = 0; f < 4; ++f)
        wC[f] = __builtin_bit_cast(short8, *(const uint4*)((const unsigned*)(P + 320) + l * 16 + f * 4));
    const floatx4 biasB = __builtin_bit_cast(floatx4, *(const float4*)(be2l + q * 4));
    floatx4 biasC[4];
    float4 w2[4];
#pragma unroll
    for (int f = 0; f < 4; ++f) {
        biasC[f] = __builtin_bit_cast(floatx4, *(const float4*)(bc1l + f * 16 + q * 4));
        w2[f]    = *(const float4*)(Wc2l + f * 16 + q * 4);
    }
    const float bc2q = (q == 0) ? bc2[layer] : 0.0f;

    const float ti = t[b * NN + i];
    const float2* cin = (const float2*)coors_in + b * NN;
    const float2 ci = cin[i];

    // shuffle sources for C-layout -> B-operand transform
    const int sA = em + ((q & 1) << 5);
    const int sB = sA + 16;

    float ax = 0.0f, ay = 0.0f;

#pragma unroll 2
    for (int tt = 0; tt < 8; ++tt) {
        const int j = tt * 16 + em;
        const float tj = t[b * NN + j];
        const float2 cj = cin[j];
        const float rx = ci.x - cj.x, ry = ci.y - cj.y;
        const float dist = rx * rx + ry * ry;

        // Stage A: fp32 VALU, result directly in C-layout (rows 4q+r, col em)
        float sA0 = fmaf(ti, a4.x, fmaf(tj, b4.x, fmaf(dist, c4.x, d4.x)));
        float sA1 = fmaf(ti, a4.y, fmaf(tj, b4.y, fmaf(dist, c4.y, d4.y)));
        float sA2 = fmaf(ti, a4.z, fmaf(tj, b4.z, fmaf(dist, c4.z, d4.z)));
        float sA3 = fmaf(ti, a4.w, fmaf(tj, b4.w, fmaf(dist, c4.w, d4.w)));
        unsigned P0 = packbf(silu_f(sA0), silu_f(sA1));
        unsigned P1 = packbf(silu_f(sA2), silu_f(sA3));
        uint4 tb;
        tb.x = (unsigned)__shfl((int)P0, sA, 64);
        tb.y = (unsigned)__shfl((int)P1, sA, 64);
        tb.z = (unsigned)__shfl((int)P0, sB, 64);
        tb.w = (unsigned)__shfl((int)P1, sB, 64);
        short8 bB = __builtin_bit_cast(short8, tb);

        // Stage B: m = silu(W2 . e1 + b2); sm = silu(m)
        floatx4 accB = __builtin_amdgcn_mfma_f32_16x16x32_bf16(wB, bB, biasB, 0, 0, 0);
        unsigned Q0 = packbf(silu_f(silu_f(accB[0])), silu_f(silu_f(accB[1])));
        unsigned Q1 = packbf(silu_f(silu_f(accB[2])), silu_f(silu_f(accB[3])));
        uint4 tc;
        tc.x = (unsigned)__shfl((int)Q0, sA, 64);
        tc.y = (unsigned)__shfl((int)Q1, sA, 64);
        tc.z = (unsigned)__shfl((int)Q0, sB, 64);
        tc.w = (unsigned)__shfl((int)Q1, sB, 64);
        short8 bC = __builtin_bit_cast(short8, tc);

        // Stage C: h = silu(Wc1 . sm + bc1), 64 channels in 4 fragments
        floatx4 h0 = __builtin_amdgcn_mfma_f32_16x16x32_bf16(wC[0], bC, biasC[0], 0, 0, 0);
        floatx4 h1 = __builtin_amdgcn_mfma_f32_16x16x32_bf16(wC[1], bC, biasC[1], 0, 0, 0);
        floatx4 h2 = __builtin_amdgcn_mfma_f32_16x16x32_bf16(wC[2], bC, biasC[2], 0, 0, 0);
        floatx4 h3 = __builtin_amdgcn_mfma_f32_16x16x32_bf16(wC[3], bC, biasC[3], 0, 0, 0);

        // Stage D: per-lane partial of w_ij over 16 of 64 channels
        float wp = bc2q;
#pragma unroll
        for (int r = 0; r < 4; ++r) wp = fmaf(silu_f(h0[r]), w2[0].x * 0.0f + ((const float*)&w2[0])[r], wp);
#pragma unroll
        for (int r = 0; r < 4; ++r) wp = fmaf(silu_f(h1[r]), ((const float*)&w2[1])[r], wp);
#pragma unroll
        for (int r = 0; r < 4; ++r) wp = fmaf(silu_f(h2[r]), ((const float*)&w2[2])[r], wp);
#pragma unroll
        for (int r = 0; r < 4; ++r) wp = fmaf(silu_f(h3[r]), ((const float*)&w2[3])[r], wp);

        ax = fmaf(wp, rx, ax);
        ay = fmaf(wp, ry, ay);
    }

    // sum agg over all 64 lanes (quads hold channel-partials, em holds edges)
#pragma unroll
    for (int m = 32; m >= 1; m >>= 1) {
        ax += __shfl_xor(ax, m, 64);
        ay += __shfl_xor(ay, m, 64);
    }

    // node update, computed uniformly on all lanes (ax/ay now uniform)
    const float2 vi = ((const float2*)vel_in + b * NN)[i];
    const float phi = ti * wv_s + bvl;
    float vx = fmaf(phi, vi.x, ax);
    float vy = fmaf(phi, vi.y, ay);
    float cx = selu_f(ci.x + vx);
    float cy = selu_f(ci.y + vy);
    vx = selu_f(vx); vy = selu_f(vy);

    if (!DO_HEAD) {
        if (l == 0) {
            ((float2*)coors_out + b * NN)[i] = make_float2(cx, cy);
            ((float2*)vel_out + b * NN)[i]   = make_float2(vx, vy);
        }
    } else {
        // conv head distributed: channel c = lane&31, butterfly-reduce 4 outs
        const float x0 = selu_f(cx), x1 = selu_f(cy);
        const float x2 = selu_f(vx), x3 = selu_f(vy);
        const int c = l & 31;
        const float4 w1 = *(const float4*)(Wconv1 + c * 4);
        const float xc = selu_f(bconv1[c] + fmaf(x0, w1.x, fmaf(x1, w1.y, fmaf(x2, w1.z, x3 * w1.w))));
        float y0 = xc * Wconv2[c];
        float y1 = xc * Wconv2[32 + c];
        float y2 = xc * Wconv2[64 + c];
        float y3 = xc * Wconv2[96 + c];
#pragma unroll
        for (int m = 16; m >= 1; m >>= 1) {
            y0 += __shfl_xor(y0, m, 64);
            y1 += __shfl_xor(y1, m, 64);
            y2 += __shfl_xor(y2, m, 64);
            y3 += __shfl_xor(y3, m, 64);
        }
        if (l == 0) {
            const int idx = (b * NN + i) * 2;
            *(float2*)(out + idx) = make_float2(y0 + bconv2[0], y1 + bconv2[1]);
            *(float2*)(out + NB * NN * 2 + idx) = make_float2(y2 + bconv2[2], y3 + bconv2[3]);
        }
    }
}

extern "C" void kernel_launch(void* const* d_in, const int* in_sizes, int n_in,
                              void* d_out, int out_size, void* d_ws, size_t ws_size,
                              hipStream_t stream) {
    const float* t      = (const float*)d_in[0];
    const float* coors  = (const float*)d_in[1];
    const float* vel    = (const float*)d_in[2];
    const float* We1    = (const float*)d_in[3];
    const float* be1    = (const float*)d_in[4];
    const float* We2    = (const float*)d_in[5];
    const float* be2    = (const float*)d_in[6];
    const float* Wc1    = (const float*)d_in[7];
    const float* bc1    = (const float*)d_in[8];
    const float* Wc2    = (const float*)d_in[9];
    const float* bc2    = (const float*)d_in[10];
    const float* Wv     = (const float*)d_in[11];
    const float* bv     = (const float*)d_in[12];
    const float* Wconv1 = (const float*)d_in[13];
    const float* bconv1 = (const float*)d_in[14];
    const float* Wconv2 = (const float*)d_in[15];
    const float* bconv2 = (const float*)d_in[16];
    float* out = (float*)d_out;

    float* ws     = (float*)d_ws;
    float* coors1 = ws;                     // B*N*2 floats
    float* vel1   = ws + NB * NN * 2;       // B*N*2 floats
    float* prep   = ws + 2 * NB * NN * 2;   // 2 layers x 2048 floats

    egnn_prep<<<dim3(1), dim3(128), 0, stream>>>(We1, be1, We2, Wc1, prep);

    const dim3 grid(2048), block(256);      // 8192 rows, 1 wave per row

    egnn_layer<false><<<grid, block, 0, stream>>>(
        t, coors, vel, prep, be2, bc1, Wc2, bc2, Wv, bv,
        Wconv1, bconv1, Wconv2, bconv2, 0, coors1, vel1, nullptr);

    egnn_layer<true><<<grid, block, 0, stream>>>(
        t, coors1, vel1, prep, be2, bc1, Wc2, bc2, Wv, bv,
        Wconv1, bconv1, Wconv2, bconv2, 1, nullptr, nullptr, out);
}

// Round 4
// 151.478 us; speedup vs baseline: 1.3210x; 1.0090x over previous
//
#include <hip/hip_runtime.h>

// EGNN, MFMA core + scale-folded SiLU chain. B=64, N=128, M=16, L=2.
// Per wave: one (b,i) row, 8 tiles of 16 edges j, processed as 4 interleaved
// pairs (2 independent chains per iteration for ILP).
//  Stage A (collapsed to 3 scalars ti/tj/dist): fp32 VALU in C-layout.
//  Stage B (16->16), C (16->64): mfma_f32_16x16x32_bf16, weights=A operand,
//    [hi;lo] bf16 split in K=32 slots (~16-bit weight precision).
//  Stage D (64->1): fp32 dot + wave butterfly reduce.
// SiLU scale-folding: all silu inputs carry a log2(e) factor, so
// silu' = x'*rcp(1+exp2(-x')) needs NO pre-exp multiply; the factor is
// absorbed by the next stage's weights (ln2*log2e = 1 -> We2/Wc1 unscaled,
// biases *log2e, Wc2 *ln2). Algebraically exact in fp32.

#define NB 64
#define NN 128
#define LOG2E 1.4426950408889634f
#define LN2f  0.6931471805599453f

typedef __attribute__((ext_vector_type(8))) short short8;
typedef __attribute__((ext_vector_type(4))) float floatx4;

__device__ __forceinline__ unsigned short f2bf(float x) {
    unsigned u = __float_as_uint(x);
    return (unsigned short)((u + 0x7FFFu + ((u >> 16) & 1u)) >> 16);
}
__device__ __forceinline__ float bf2f(unsigned short b) {
    return __uint_as_float(((unsigned)b) << 16);
}
// pack two f32 -> bf16x2 (round-half-up): 2 adds + 1 v_perm
__device__ __forceinline__ unsigned packbf(float x, float y) {
    unsigned xb = __float_as_uint(x) + 0x8000u;
    unsigned yb = __float_as_uint(y) + 0x8000u;
    return __builtin_amdgcn_perm(yb, xb, 0x07060302u);
}
// input xs = x*log2e; returns silu(x)*log2e
__device__ __forceinline__ float silu_s(float xs) {
    float e = __builtin_amdgcn_exp2f(-xs);
    return xs * __builtin_amdgcn_rcpf(1.0f + e);
}
__device__ __forceinline__ float selu_f(float x) {
    const float alpha = 1.6732632423543772f;
    const float scale = 1.0507009873554805f;
    float neg = alpha * (__expf(x) - 1.0f);
    return scale * (x > 0.0f ? x : neg);
}

// ---- prep: collapsed/scaled We1 coeffs, bf16 hi/lo frags, scaled biases ----
// ws float layout per layer (stride 2048 floats):
//  [0,16)A' [16,32)B' [32,48)C' [48,64)D'   (all *log2e, D' includes be1)
//  [64,320) wB frags   [320,1344) wC frags
//  [1344,1360) be2*log2e  [1360,1424) bc1*log2e  [1424,1488) Wc2*ln2
__global__ __launch_bounds__(128) void egnn_prep(
    const float* __restrict__ We1, const float* __restrict__ be1,
    const float* __restrict__ We2, const float* __restrict__ be2,
    const float* __restrict__ Wc1, const float* __restrict__ bc1,
    const float* __restrict__ Wc2,
    float* __restrict__ prep)
{
    const int layer = threadIdx.x >> 6;
    const int l = threadIdx.x & 63;
    const int q = l >> 4, em = l & 15;
    const float* We1l = We1 + layer * 128;
    const float* be1l = be1 + layer * 16;
    const float* We2l = We2 + layer * 256;
    const float* be2l = be2 + layer * 16;
    const float* Wc1l = Wc1 + layer * 1024;
    const float* bc1l = bc1 + layer * 64;
    const float* Wc2l = Wc2 + layer * 64;
    float* P = prep + layer * 2048;

    if (l < 16) {
        P[l]      = (We1l[l] + We1l[16 + l] + We1l[32 + l]) * LOG2E;
        P[16 + l] = (We1l[48 + l] + We1l[64 + l] + We1l[80 + l]) * LOG2E;
        P[32 + l] = We1l[96 + l] * LOG2E;
        P[48 + l] = (We1l[112 + l] + be1l[l]) * LOG2E;
        P[1344 + l] = be2l[l] * LOG2E;
    }
    P[1360 + l] = bc1l[l] * LOG2E;
    P[1424 + l] = Wc2l[l] * LN2f;

    // wB: A[m=em][k=q*8+j], k<16 -> hi(We2[k][m]), else lo(We2[k-16][m])
    {
        unsigned wb[4];
#pragma unroll
        for (int d = 0; d < 4; ++d) {
            unsigned short sv[2];
#pragma unroll
            for (int e = 0; e < 2; ++e) {
                int k = q * 8 + 2 * d + e;
                float w = We2l[(k & 15) * 16 + em];
                unsigned short hv = f2bf(w);
                unsigned short lv = f2bf(w - bf2f(hv));
                sv[e] = (k < 16) ? hv : lv;
            }
            wb[d] = (unsigned)sv[0] | ((unsigned)sv[1] << 16);
        }
        *(uint4*)((unsigned*)(P + 64) + l * 4) = make_uint4(wb[0], wb[1], wb[2], wb[3]);
    }
    // wC: 4 fragments of 16 out-channels each
#pragma unroll
    for (int f = 0; f < 4; ++f) {
        unsigned wc[4];
#pragma unroll
        for (int d = 0; d < 4; ++d) {
            unsigned short sv[2];
#pragma unroll
            for (int e = 0; e < 2; ++e) {
                int k = q * 8 + 2 * d + e;
                float w = Wc1l[(k & 15) * 64 + 16 * f + em];
                unsigned short hv = f2bf(w);
                unsigned short lv = f2bf(w - bf2f(hv));
                sv[e] = (k < 16) ? hv : lv;
            }
            wc[d] = (unsigned)sv[0] | ((unsigned)sv[1] << 16);
        }
        *(uint4*)((unsigned*)(P + 320) + l * 16 + f * 4) = make_uint4(wc[0], wc[1], wc[2], wc[3]);
    }
}

template <bool DO_HEAD>
__global__ __launch_bounds__(256) void egnn_layer(
    const float* __restrict__ t,
    const float* __restrict__ coors_in,
    const float* __restrict__ vel_in,
    const float* __restrict__ prep,
    const float* __restrict__ bc2,
    const float* __restrict__ Wv,  const float* __restrict__ bv,
    const float* __restrict__ Wconv1, const float* __restrict__ bconv1,
    const float* __restrict__ Wconv2, const float* __restrict__ bconv2,
    int layer,
    float* __restrict__ coors_out, float* __restrict__ vel_out,
    float* __restrict__ out)
{
    const int l   = threadIdx.x & 63;
    const int wvi = threadIdx.x >> 6;
    const int row = blockIdx.x * 4 + wvi;     // b*128 + i
    const int b   = row >> 7;
    const int i   = row & 127;
    const int q   = l >> 4;                   // quad 0..3
    const int em  = l & 15;                   // edge-in-tile / out-row group

    const float* P = prep + layer * 2048;
    const float  wv_s = Wv[layer * 3 + 0] + Wv[layer * 3 + 1] + Wv[layer * 3 + 2];
    const float  bvl  = bv[layer];

    // prologue: per-lane fragment loads (L2-hot prep)
    const float4 a4 = *(const float4*)(P + 0  + q * 4);
    const float4 b4 = *(const float4*)(P + 16 + q * 4);
    const float4 c4 = *(const float4*)(P + 32 + q * 4);
    const float4 d4 = *(const float4*)(P + 48 + q * 4);
    const short8 wB = __builtin_bit_cast(short8, *(const uint4*)((const unsigned*)(P + 64) + l * 4));
    short8 wC[4];
#pragma unroll
    for (int f = 0; f < 4; ++f)
        wC[f] = __builtin_bit_cast(short8, *(const uint4*)((const unsigned*)(P + 320) + l * 16 + f * 4));
    const floatx4 biasB = __builtin_bit_cast(floatx4, *(const float4*)(P + 1344 + q * 4));
    floatx4 biasC[4];
    float4 w2[4];
#pragma unroll
    for (int f = 0; f < 4; ++f) {
        biasC[f] = __builtin_bit_cast(floatx4, *(const float4*)(P + 1360 + f * 16 + q * 4));
        w2[f]    = *(const float4*)(P + 1424 + f * 16 + q * 4);
    }
    const float bc2q = (q == 0) ? bc2[layer] : 0.0f;

    const float* tptr = t + b * NN;
    const float ti = tptr[i];
    const float2* cin = (const float2*)coors_in + b * NN;
    const float2 ci = cin[i];

    // shuffle sources for C-layout -> B-operand transform (loop-invariant)
    const int sA = em + ((q & 1) << 5);
    const int sB = sA + 16;

    float ax = 0.0f, ay = 0.0f;

#pragma unroll 1
    for (int tt = 0; tt < 8; tt += 2) {
        // two independent tile chains (p = 0,1) interleaved for ILP
        float tj[2], rx[2], ry[2], dist[2];
#pragma unroll
        for (int p = 0; p < 2; ++p) {
            const int j = (tt + p) * 16 + em;
            tj[p] = tptr[j];
            const float2 cj = cin[j];
            rx[p] = ci.x - cj.x;
            ry[p] = ci.y - cj.y;
            dist[p] = fmaf(rx[p], rx[p], ry[p] * ry[p]);
        }
        uint4 tb[2];
#pragma unroll
        for (int p = 0; p < 2; ++p) {
            // Stage A: fp32, result in C-layout (rows 4q+r, col em), *log2e
            float s0 = fmaf(ti, a4.x, fmaf(tj[p], b4.x, fmaf(dist[p], c4.x, d4.x)));
            float s1 = fmaf(ti, a4.y, fmaf(tj[p], b4.y, fmaf(dist[p], c4.y, d4.y)));
            float s2 = fmaf(ti, a4.z, fmaf(tj[p], b4.z, fmaf(dist[p], c4.z, d4.z)));
            float s3 = fmaf(ti, a4.w, fmaf(tj[p], b4.w, fmaf(dist[p], c4.w, d4.w)));
            unsigned P0 = packbf(silu_s(s0), silu_s(s1));
            unsigned P1 = packbf(silu_s(s2), silu_s(s3));
            tb[p].x = (unsigned)__shfl((int)P0, sA, 64);
            tb[p].y = (unsigned)__shfl((int)P1, sA, 64);
            tb[p].z = (unsigned)__shfl((int)P0, sB, 64);
            tb[p].w = (unsigned)__shfl((int)P1, sB, 64);
        }
        floatx4 accB[2];
#pragma unroll
        for (int p = 0; p < 2; ++p)
            accB[p] = __builtin_amdgcn_mfma_f32_16x16x32_bf16(
                wB, __builtin_bit_cast(short8, tb[p]), biasB, 0, 0, 0);
        uint4 tc[2];
#pragma unroll
        for (int p = 0; p < 2; ++p) {
            unsigned Q0 = packbf(silu_s(silu_s(accB[p][0])), silu_s(silu_s(accB[p][1])));
            unsigned Q1 = packbf(silu_s(silu_s(accB[p][2])), silu_s(silu_s(accB[p][3])));
            tc[p].x = (unsigned)__shfl((int)Q0, sA, 64);
            tc[p].y = (unsigned)__shfl((int)Q1, sA, 64);
            tc[p].z = (unsigned)__shfl((int)Q0, sB, 64);
            tc[p].w = (unsigned)__shfl((int)Q1, sB, 64);
        }
        floatx4 h[2][4];
#pragma unroll
        for (int p = 0; p < 2; ++p) {
            const short8 bC = __builtin_bit_cast(short8, tc[p]);
            h[p][0] = __builtin_amdgcn_mfma_f32_16x16x32_bf16(wC[0], bC, biasC[0], 0, 0, 0);
            h[p][1] = __builtin_amdgcn_mfma_f32_16x16x32_bf16(wC[1], bC, biasC[1], 0, 0, 0);
            h[p][2] = __builtin_amdgcn_mfma_f32_16x16x32_bf16(wC[2], bC, biasC[2], 0, 0, 0);
            h[p][3] = __builtin_amdgcn_mfma_f32_16x16x32_bf16(wC[3], bC, biasC[3], 0, 0, 0);
        }
#pragma unroll
        for (int p = 0; p < 2; ++p) {
            float wp = bc2q;
#pragma unroll
            for (int f = 0; f < 4; ++f) {
                wp = fmaf(silu_s(h[p][f][0]), ((const float*)&w2[f])[0], wp);
                wp = fmaf(silu_s(h[p][f][1]), ((const float*)&w2[f])[1], wp);
                wp = fmaf(silu_s(h[p][f][2]), ((const float*)&w2[f])[2], wp);
                wp = fmaf(silu_s(h[p][f][3]), ((const float*)&w2[f])[3], wp);
            }
            ax = fmaf(wp, rx[p], ax);
            ay = fmaf(wp, ry[p], ay);
        }
    }

    // sum agg over all 64 lanes (quads hold channel-partials, em holds edges)
#pragma unroll
    for (int m = 32; m >= 1; m >>= 1) {
        ax += __shfl_xor(ax, m, 64);
        ay += __shfl_xor(ay, m, 64);
    }

    // node update, computed uniformly on all lanes (ax/ay now uniform)
    const float2 vi = ((const float2*)vel_in + b * NN)[i];
    const float phi = fmaf(ti, wv_s, bvl);
    float vx = fmaf(phi, vi.x, ax);
    float vy = fmaf(phi, vi.y, ay);
    float cx = selu_f(ci.x + vx);
    float cy = selu_f(ci.y + vy);
    vx = selu_f(vx); vy = selu_f(vy);

    if (!DO_HEAD) {
        if (l == 0) {
            ((float2*)coors_out + b * NN)[i] = make_float2(cx, cy);
            ((float2*)vel_out + b * NN)[i]   = make_float2(vx, vy);
        }
    } else {
        // conv head distributed: channel c = lane&31, butterfly-reduce 4 outs
        const float x0 = selu_f(cx), x1 = selu_f(cy);
        const float x2 = selu_f(vx), x3 = selu_f(vy);
        const int c = l & 31;
        const float4 w1 = *(const float4*)(Wconv1 + c * 4);
        const float xc = selu_f(bconv1[c] + fmaf(x0, w1.x, fmaf(x1, w1.y, fmaf(x2, w1.z, x3 * w1.w))));
        float y0 = xc * Wconv2[c];
        float y1 = xc * Wconv2[32 + c];
        float y2 = xc * Wconv2[64 + c];
        float y3 = xc * Wconv2[96 + c];
#pragma unroll
        for (int m = 16; m >= 1; m >>= 1) {
            y0 += __shfl_xor(y0, m, 64);
            y1 += __shfl_xor(y1, m, 64);
            y2 += __shfl_xor(y2, m, 64);
            y3 += __shfl_xor(y3, m, 64);
        }
        if (l == 0) {
            const int idx = (b * NN + i) * 2;
            *(float2*)(out + idx) = make_float2(y0 + bconv2[0], y1 + bconv2[1]);
            *(float2*)(out + NB * NN * 2 + idx) = make_float2(y2 + bconv2[2], y3 + bconv2[3]);
        }
    }
}

extern "C" void kernel_launch(void* const* d_in, const int* in_sizes, int n_in,
                              void* d_out, int out_size, void* d_ws, size_t ws_size,
                              hipStream_t stream) {
    const float* t      = (const float*)d_in[0];
    const float* coors  = (const float*)d_in[1];
    const float* vel    = (const float*)d_in[2];
    const float* We1    = (const float*)d_in[3];
    const float* be1    = (const float*)d_in[4];
    const float* We2    = (const float*)d_in[5];
    const float* be2    = (const float*)d_in[6];
    const float* Wc1    = (const float*)d_in[7];
    const float* bc1    = (const float*)d_in[8];
    const float* Wc2    = (const float*)d_in[9];
    const float* bc2    = (const float*)d_in[10];
    const float* Wv     = (const float*)d_in[11];
    const float* bv     = (const float*)d_in[12];
    const float* Wconv1 = (const float*)d_in[13];
    const float* bconv1 = (const float*)d_in[14];
    const float* Wconv2 = (const float*)d_in[15];
    const float* bconv2 = (const float*)d_in[16];
    float* out = (float*)d_out;

    float* ws     = (float*)d_ws;
    float* coors1 = ws;                     // B*N*2 floats
    float* vel1   = ws + NB * NN * 2;       // B*N*2 floats
    float* prep   = ws + 2 * NB * NN * 2;   // 2 layers x 2048 floats

    egnn_prep<<<dim3(1), dim3(128), 0, stream>>>(We1, be1, We2, be2, Wc1, bc1, Wc2, prep);

    const dim3 grid(2048), block(256);      // 8192 rows, 1 wave per row

    egnn_layer<false><<<grid, block, 0, stream>>>(
        t, coors, vel, prep, bc2, Wv, bv,
        Wconv1, bconv1, Wconv2, bconv2, 0, coors1, vel1, nullptr);

    egnn_layer<true><<<grid, block, 0, stream>>>(
        t, coors1, vel1, prep, bc2, Wv, bv,
        Wconv1, bconv1, Wconv2, bconv2, 1, nullptr, nullptr, out);
}